// Round 15
// baseline (247.579 us; speedup 1.0000x reference)
//
#include <hip/hip_runtime.h>
#include <cstdint>
#include <cstddef>

typedef _Float16 f16;
typedef _Float16 f16x8 __attribute__((ext_vector_type(8)));
typedef _Float16 f16x4 __attribute__((ext_vector_type(4)));
typedef float f32x4 __attribute__((ext_vector_type(4)));

#define AS1 __attribute__((address_space(1)))
#define AS3 __attribute__((address_space(3)))

__device__ __forceinline__ void gl_lds16(const void* g, void* l) {
    __builtin_amdgcn_global_load_lds((const AS1 uint32_t*)g, (AS3 uint32_t*)l, 16, 0, 0);
}

__device__ __forceinline__ f16x8 relu8(f16x8 x) {
    f16x8 z = {};
    return __builtin_elementwise_max(x, z);
}

// ===========================================================================
// XOR-slot swizzle (verified r9-r13: conflict-free + coalesced):
//   LDS row-major [ROWS][32] f16; row r's global chunk c at slot c^((r>>1)&3).
//   Staging granule g: row=g>>2, slot=g&3, source chunk (g&3)^((g>>3)&3).
//   Read slot for k-chunk lk at row r: lk^((r>>1)&3).
// ===========================================================================

// ---------------------------------------------------------------------------
// MEGA-FUSED edge kernel: AGG[node,:] = sum_{7 edges} relu(LN(
//     relu(P[src]+Q[tgt]) @ ew2^T + eb2 )*g+b).   E2 buffer DELETED.
// Tile 112 edge rows (=2 batches=16 nodes, node-aligned) x 512 cols.
// 8 waves 1Mx8N: wave = 112x64, acc[7][4] f32x4 = 112 VGPR.
// K-loop: r13 2-buffer counted-vmcnt; waves 0-1 also stage PQl -> vmcnt(5),
// waves 2-7 vmcnt(4). Epilogue: bias -> LN stats (lnred/stat) -> per-wave
// node-aggregate into aggw[16][64] f32 (over dead Bs region; lk-turn
// serialized RMW, 16 consecutive banks = conflict-free) -> coalesced AGG.
// ---------------------------------------------------------------------------
__global__ __launch_bounds__(512, 2)
void edge_ln_agg_kernel(const f16* __restrict__ PQ, const f16* __restrict__ W,
                        const float* __restrict__ eb2,
                        const float* __restrict__ g, const float* __restrict__ b,
                        f16* __restrict__ AGG)
{
    __shared__ char smem[77824];
    f16*   BsB   = (f16*)smem;                    // [2][512*32] = 64KB
    f16*   PQlB  = (f16*)(smem + 65536);          // [2][32*32]  =  4KB
    float* lnred = (float*)(smem + 69632);        // [112][8][2] =  7KB
    float* stat  = (float*)(smem + 76800);        // [112][2]    =  896B

    const int tid  = threadIdx.x;
    const int wave = tid >> 6, lane = tid & 63;
    const int wn = wave;                          // 1M x 8N
    const int lr = lane & 15, lk = lane >> 4;
    const int blk = blockIdx.x;                   // 112 edge rows each
    const int row0 = blk * 112;
    const int n0 = blk << 4;                      // 16 nodes per block

    // ---- staging addresses ----
    const int c16 = (((tid & 3) ^ ((tid >> 3) & 3)) << 3);
    const f16* Wg = W + (size_t)(tid >> 2) * 512 + c16;      // rows tid>>2 (+128i)
    const int prow = tid >> 2;                               // 0..31 (tid<128)
    const f16* PQg = PQ + (size_t)(n0 + (prow & 15)) * 1024
                   + ((prow >> 4) << 9) + c16;               // P rows / Q rows

    // ---- per-lane A-fragment addrs (A row = mi*16 + lr) ----
    int addrP[7], addrQ[7];
#pragma unroll
    for (int mi = 0; mi < 7; ++mi) {
        int er = row0 + mi * 16 + lr;
        int bb = er / 56;
        int e  = er - bb * 56;
        int r  = e / 7;
        int t2 = e - r * 7;
        int cn = t2 + (t2 >= r ? 1 : 0);
        int pl = ((bb - 2 * blk) << 3) + r;
        int ql = ((bb - 2 * blk) << 3) + cn;
        addrP[mi] = pl * 32 + ((lk ^ ((pl >> 1) & 3)) << 3);
        addrQ[mi] = 512 + ql * 32 + ((lk ^ ((ql >> 1) & 3)) << 3);
    }
    const int kx = (lk ^ ((lr >> 1) & 3)) << 3;   // B read slot

    f32x4 acc[7][4] = {};

#define STAGE(buf, k0)                                                        \
    do {                                                                      \
        _Pragma("unroll")                                                     \
        for (int i_ = 0; i_ < 4; ++i_)                                        \
            gl_lds16(Wg + (k0) + (size_t)(i_ * 128) * 512,                    \
                     &BsB[(size_t)(buf) * 16384 + (i_ * 512 + tid) * 8]);     \
        if (tid < 128)                                                        \
            gl_lds16(PQg + (k0), &PQlB[(size_t)(buf) * 1024 + tid * 8]);      \
    } while (0)

    STAGE(0, 0);
    for (int t = 0; t < 16; ++t) {
        const int cur = t & 1;
        if (t + 1 < 16) {
            STAGE(cur ^ 1, (t + 1) << 5);
            if (wave < 2) asm volatile("s_waitcnt vmcnt(5)" ::: "memory");
            else          asm volatile("s_waitcnt vmcnt(4)" ::: "memory");
        } else {
            asm volatile("s_waitcnt vmcnt(0)" ::: "memory");
        }
        __builtin_amdgcn_s_barrier();
        __builtin_amdgcn_sched_barrier(0);

        const f16* Pc = &PQlB[(size_t)cur * 1024];
        const f16* Bc = &BsB[(size_t)cur * 16384];
        f16x8 af[7], bf[4];
#pragma unroll
        for (int mi = 0; mi < 7; ++mi) {
            f16x8 p = *(const f16x8*)&Pc[addrP[mi]];
            f16x8 q = *(const f16x8*)&Pc[addrQ[mi]];
            af[mi] = relu8(p + q);
        }
#pragma unroll
        for (int ni = 0; ni < 4; ++ni)
            bf[ni] = *(const f16x8*)&Bc[(wn * 64 + ni * 16 + lr) * 32 + kx];
#pragma unroll
        for (int mi = 0; mi < 7; ++mi)
#pragma unroll
            for (int ni = 0; ni < 4; ++ni)
                acc[mi][ni] = __builtin_amdgcn_mfma_f32_16x16x32_f16(
                    af[mi], bf[ni], acc[mi][ni], 0, 0, 0);

        __builtin_amdgcn_sched_barrier(0);
        __builtin_amdgcn_s_barrier();
    }
#undef STAGE

    // ---- epilogue: bias -> LN stats -> normalize+relu -> node aggregate ----
    float eb2v[4], gv[4], bv[4];
#pragma unroll
    for (int ni = 0; ni < 4; ++ni) {
        int col = wn * 64 + ni * 16 + lr;
        eb2v[ni] = eb2[col]; gv[ni] = g[col]; bv[ni] = b[col];
    }
#pragma unroll
    for (int mi = 0; mi < 7; ++mi)
#pragma unroll
        for (int ni = 0; ni < 4; ++ni)
#pragma unroll
            for (int j = 0; j < 4; ++j)
                acc[mi][ni][j] += eb2v[ni];

#pragma unroll
    for (int mi = 0; mi < 7; ++mi) {
#pragma unroll
        for (int j = 0; j < 4; ++j) {
            float s = 0.f, s2 = 0.f;
#pragma unroll
            for (int ni = 0; ni < 4; ++ni) {
                float v = acc[mi][ni][j];
                s += v; s2 += v * v;
            }
#pragma unroll
            for (int o = 1; o < 16; o <<= 1) {
                s  += __shfl_xor(s,  o, 64);
                s2 += __shfl_xor(s2, o, 64);
            }
            if (lr == 0) {
                int row = mi * 16 + lk * 4 + j;
                lnred[(row * 8 + wn) * 2 + 0] = s;
                lnred[(row * 8 + wn) * 2 + 1] = s2;
            }
        }
    }
    __syncthreads();
    if (tid < 112) {
        float s = 0.f, s2 = 0.f;
#pragma unroll
        for (int w = 0; w < 8; ++w) {
            s  += lnred[(tid * 8 + w) * 2 + 0];
            s2 += lnred[(tid * 8 + w) * 2 + 1];
        }
        float mean = s * (1.0f / 512.0f);
        float var  = fmaxf(s2 * (1.0f / 512.0f) - mean * mean, 0.0f);
        stat[tid * 2 + 0] = mean;
        stat[tid * 2 + 1] = rsqrtf(var + 1e-5f);
    }
    __syncthreads();

    // per-wave aggregate region (over dead Bs area): aggw[16 nodes][64 cols]
    float* aggw = (float*)smem + wave * 1024;
#pragma unroll
    for (int i = 0; i < 16; ++i) aggw[i * 64 + lane] = 0.f;
    asm volatile("s_waitcnt lgkmcnt(0)" ::: "memory");
    for (int turn = 0; turn < 4; ++turn) {
        if (lk == turn) {
#pragma unroll
            for (int mi = 0; mi < 7; ++mi) {
#pragma unroll
                for (int j = 0; j < 4; ++j) {
                    int row = mi * 16 + lk * 4 + j;
                    float mean = stat[row * 2 + 0];
                    float rstd = stat[row * 2 + 1];
                    int gg = row / 7;
#pragma unroll
                    for (int ni = 0; ni < 4; ++ni) {
                        float y = fmaxf((acc[mi][ni][j] - mean) * rstd * gv[ni] + bv[ni], 0.f);
                        aggw[gg * 64 + ni * 16 + lr] += y;
                    }
                }
            }
        }
    }
    asm volatile("s_waitcnt lgkmcnt(0)" ::: "memory");
#pragma unroll
    for (int i = 0; i < 16; ++i)
        AGG[(size_t)(n0 + i) * 512 + wn * 64 + lane] = (f16)aggw[i * 64 + lane];
}

// ===========================================================================
// XOR-slot swizzled 128x256 GEMM (r10-r13 verified). PQ (K=128), ew3, nw1.
// launch_bounds MUST stay (256,2): (256,4) spills acc (r9).
// ===========================================================================
template<bool RELU>
__global__ __launch_bounds__(256, 2)
void gemm_swz_kernel(const f16* __restrict__ A, int lda,
                     const f16* __restrict__ W, int ldw,
                     const float* __restrict__ bias, float bscale,
                     f16* __restrict__ C, int ldc, int K)
{
    __shared__ f16 As[2][4096];
    __shared__ f16 Bs[2][8192];
    const int tid  = threadIdx.x;
    const int wave = tid >> 6, lane = tid & 63;
    const int wm = wave >> 1, wn = wave & 1;
    const int lr = lane & 15, lk = lane >> 4;
    const int row0 = blockIdx.y << 7;
    const int col0 = blockIdx.x << 8;

    const int c16 = (((tid & 3) ^ ((tid >> 3) & 3)) << 3);
    const f16* Ag = A + (size_t)(row0 + (tid >> 2)) * lda + c16;
    const f16* Wg = W + (size_t)(col0 + (tid >> 2)) * ldw + c16;
    const int kx = (lk ^ ((lr >> 1) & 3)) << 3;

    f32x4 acc[4][8] = {};

#define STAGE(buf, k0)                                                        \
    do {                                                                      \
        gl_lds16(Ag + (k0),                      &As[buf][tid * 8]);          \
        gl_lds16(Ag + (k0) + (size_t)64 * lda,   &As[buf][(tid + 256) * 8]);  \
        _Pragma("unroll")                                                     \
        for (int i_ = 0; i_ < 4; ++i_)                                        \
            gl_lds16(Wg + (k0) + (size_t)(i_ * 64) * ldw,                     \
                     &Bs[buf][(i_ * 256 + tid) * 8]);                         \
    } while (0)

    const int nt = K >> 5;
    STAGE(0, 0);
    for (int t = 0; t < nt; ++t) {
        const int cur = t & 1;
        if (t + 1 < nt) {
            STAGE(cur ^ 1, (t + 1) << 5);
            asm volatile("s_waitcnt vmcnt(6)" ::: "memory");
        } else {
            asm volatile("s_waitcnt vmcnt(0)" ::: "memory");
        }
        __builtin_amdgcn_s_barrier();
        __builtin_amdgcn_sched_barrier(0);

        f16x8 af[4], bf[8];
#pragma unroll
        for (int i = 0; i < 4; ++i)
            af[i] = *(const f16x8*)&As[cur][(wm * 64 + i * 16 + lr) * 32 + kx];
#pragma unroll
        for (int i = 0; i < 8; ++i)
            bf[i] = *(const f16x8*)&Bs[cur][(wn * 128 + i * 16 + lr) * 32 + kx];
#pragma unroll
        for (int mi = 0; mi < 4; ++mi)
#pragma unroll
            for (int ni = 0; ni < 8; ++ni)
                acc[mi][ni] = __builtin_amdgcn_mfma_f32_16x16x32_f16(
                    af[mi], bf[ni], acc[mi][ni], 0, 0, 0);

        __builtin_amdgcn_sched_barrier(0);
        __builtin_amdgcn_s_barrier();
    }
#undef STAGE

#pragma unroll
    for (int mi = 0; mi < 4; ++mi) {
#pragma unroll
        for (int ni = 0; ni < 8; ++ni) {
#pragma unroll
            for (int j = 0; j < 4; ++j) {
                int r = row0 + wm * 64 + mi * 16 + lk * 4 + j;
                int c = col0 + wn * 128 + ni * 16 + lr;
                float v = acc[mi][ni][j] + bias[c] * bscale;
                if (RELU) v = fmaxf(v, 0.0f);
                C[(size_t)r * ldc + c] = (f16)v;
            }
        }
    }
}

// ---------------------------------------------------------------------------
// Small GEMM (N=128; used once for nw3): 128x128 tile, legacy layout.
// ---------------------------------------------------------------------------
template<bool BIAS, bool RELU>
__global__ __launch_bounds__(256, 2)
void gemm_kernel(const f16* __restrict__ A, int lda,
                 const f16* __restrict__ W, int ldw,
                 const float* __restrict__ bias, float bscale,
                 f16* __restrict__ C, int ldc, int K)
{
    __shared__ f16 As[4096];
    __shared__ f16 Bs[4096];
    const int tid  = threadIdx.x;
    const int wave = tid >> 6;
    const int lane = tid & 63;
    const int wm = wave >> 1, wn = wave & 1;
    const int lr = lane & 15, lk = lane >> 4;
    const int row0 = blockIdx.y << 7;
    const int col0 = blockIdx.x << 7;

    const int srow = tid >> 2;
    const int scol = (tid & 3) << 3;
    const f16* Ag = A + (size_t)(row0 + srow) * lda + scol;
    const f16* Wg = W + (size_t)(col0 + srow) * ldw + scol;
    f16* lA0 = &As[wave * 512];
    f16* lA1 = &As[2048 + wave * 512];
    f16* lB0 = &Bs[wave * 512];
    f16* lB1 = &Bs[2048 + wave * 512];

    f32x4 acc[4][4] = {};

    for (int k0 = 0; k0 < K; k0 += 32) {
        if (k0) __syncthreads();
        gl_lds16(Ag + k0,                    lA0);
        gl_lds16(Ag + k0 + (size_t)64 * lda, lA1);
        gl_lds16(Wg + k0,                    lB0);
        gl_lds16(Wg + k0 + (size_t)64 * ldw, lB1);
        __syncthreads();

        f16x8 af[4], bf[4];
#pragma unroll
        for (int i = 0; i < 4; ++i)
            af[i] = *(const f16x8*)&As[(wm * 64 + i * 16 + lr) * 32 + lk * 8];
#pragma unroll
        for (int i = 0; i < 4; ++i)
            bf[i] = *(const f16x8*)&Bs[(wn * 64 + i * 16 + lr) * 32 + lk * 8];
#pragma unroll
        for (int mi = 0; mi < 4; ++mi)
#pragma unroll
            for (int ni = 0; ni < 4; ++ni)
                acc[mi][ni] = __builtin_amdgcn_mfma_f32_16x16x32_f16(
                    af[mi], bf[ni], acc[mi][ni], 0, 0, 0);
    }

#pragma unroll
    for (int mi = 0; mi < 4; ++mi) {
#pragma unroll
        for (int ni = 0; ni < 4; ++ni) {
#pragma unroll
            for (int j = 0; j < 4; ++j) {
                int r = row0 + wm * 64 + mi * 16 + lk * 4 + j;
                int c = col0 + wn * 64 + ni * 16 + lr;
                float v = acc[mi][ni][j];
                if (BIAS) v += bias[c] * bscale;
                if (RELU) v = fmaxf(v, 0.0f);
                C[(size_t)r * ldc + c] = (f16)v;
            }
        }
    }
}

// ---------------------------------------------------------------------------
// Fused GEMM + bias + LayerNorm + relu (node MLP layer 2). BM=64, 8 waves,
// K=512, W row-stride 512. XOR-slot swizzled staging (coalesced).
// ---------------------------------------------------------------------------
__global__ __launch_bounds__(512, 2)
void fused_gemm_ln(const f16* __restrict__ A, int lda,
                   const f16* __restrict__ W,
                   const float* __restrict__ bias,
                   const float* __restrict__ g, const float* __restrict__ b,
                   f16* __restrict__ C, int ldc)
{
    constexpr int BM = 64, NI = 4, NWN = 8;
    __shared__ f16 As[BM * 32];
    __shared__ f16 Bs[512 * 32];
    __shared__ float lnred[BM * NWN * 2];
    __shared__ float stat[BM * 2];

    const int tid  = threadIdx.x;
    const int wave = tid >> 6;
    const int lane = tid & 63;
    const int wn = wave;
    const int lr = lane & 15, lk = lane >> 4;
    const int row0 = blockIdx.x * BM;
    const int wcol0 = wn * (NI * 16);

    const int c16 = (((tid & 3) ^ ((tid >> 3) & 3)) << 3);
    const f16* Ar = A + (size_t)(row0 + (tid >> 2)) * lda + c16;
    const f16* Wr = W + (size_t)(tid >> 2) * 512 + c16;
    const int kx = (lk ^ ((lr >> 1) & 3)) << 3;

    f32x4 acc[4][NI] = {};

    for (int k0 = 0; k0 < 512; k0 += 32) {
        if (k0) __syncthreads();
#pragma unroll
        for (int i = 0; i < 4; ++i)
            gl_lds16(Wr + k0 + (size_t)(i * 128) * 512, &Bs[(i * 512 + tid) * 8]);
        if (tid < 256)
            gl_lds16(Ar + k0, &As[tid * 8]);
        __syncthreads();

        f16x8 af[4], bf[NI];
#pragma unroll
        for (int i = 0; i < 4; ++i)
            af[i] = *(const f16x8*)&As[(i * 16 + lr) * 32 + kx];
#pragma unroll
        for (int i = 0; i < NI; ++i)
            bf[i] = *(const f16x8*)&Bs[(wcol0 + i * 16 + lr) * 32 + kx];
#pragma unroll
        for (int mi = 0; mi < 4; ++mi)
#pragma unroll
            for (int ni = 0; ni < NI; ++ni)
                acc[mi][ni] = __builtin_amdgcn_mfma_f32_16x16x32_f16(
                    af[mi], bf[ni], acc[mi][ni], 0, 0, 0);
    }

    float biasv[NI], gv[NI], bv[NI];
#pragma unroll
    for (int ni = 0; ni < NI; ++ni) {
        int col = wcol0 + ni * 16 + lr;
        biasv[ni] = bias[col];
        gv[ni] = g[col];
        bv[ni] = b[col];
    }
#pragma unroll
    for (int mi = 0; mi < 4; ++mi)
#pragma unroll
        for (int ni = 0; ni < NI; ++ni)
#pragma unroll
            for (int j = 0; j < 4; ++j)
                acc[mi][ni][j] += biasv[ni];

#pragma unroll
    for (int mi = 0; mi < 4; ++mi) {
#pragma unroll
        for (int j = 0; j < 4; ++j) {
            float s = 0.f, s2 = 0.f;
#pragma unroll
            for (int ni = 0; ni < NI; ++ni) {
                float v = acc[mi][ni][j];
                s += v; s2 += v * v;
            }
#pragma unroll
            for (int o = 1; o < 16; o <<= 1) {
                s  += __shfl_xor(s,  o, 64);
                s2 += __shfl_xor(s2, o, 64);
            }
            if (lr == 0) {
                int row = mi * 16 + lk * 4 + j;
                lnred[(row * NWN + wn) * 2 + 0] = s;
                lnred[(row * NWN + wn) * 2 + 1] = s2;
            }
        }
    }
    __syncthreads();
    if (tid < BM) {
        float s = 0.f, s2 = 0.f;
#pragma unroll
        for (int w = 0; w < NWN; ++w) {
            s  += lnred[(tid * NWN + w) * 2 + 0];
            s2 += lnred[(tid * NWN + w) * 2 + 1];
        }
        float mean = s * (1.0f / 512.0f);
        float var  = fmaxf(s2 * (1.0f / 512.0f) - mean * mean, 0.0f);
        stat[tid * 2 + 0] = mean;
        stat[tid * 2 + 1] = rsqrtf(var + 1e-5f);
    }
    __syncthreads();

#pragma unroll
    for (int mi = 0; mi < 4; ++mi) {
#pragma unroll
        for (int j = 0; j < 4; ++j) {
            int row = mi * 16 + lk * 4 + j;
            float mean = stat[row * 2 + 0];
            float rstd = stat[row * 2 + 1];
            size_t gr = (size_t)(row0 + row) * ldc;
#pragma unroll
            for (int ni = 0; ni < NI; ++ni) {
                float y = (acc[mi][ni][j] - mean) * rstd * gv[ni] + bv[ni];
                C[gr + wcol0 + ni * 16 + lr] = (f16)fmaxf(y, 0.0f);
            }
        }
    }
}

// ---------------------------------------------------------------------------
// Convert fp32 -> f16. Slots strided into XCAT cols 0:128 (ldc=640).
// ew1 repacked: w_ew1x[1024][128]; eb1x[1024] f32 = 0.5*[eb1 ; eb1].
// ---------------------------------------------------------------------------
__global__ void convert_all_kernel(
    const float* __restrict__ s0, f16* __restrict__ xcat,
    const float* __restrict__ s1, f16* __restrict__ d1,
    const float* __restrict__ s2, f16* __restrict__ d2,
    const float* __restrict__ s3, f16* __restrict__ d3,
    const float* __restrict__ s4, f16* __restrict__ d4,
    const float* __restrict__ s5, f16* __restrict__ d5,
    const float* __restrict__ s6, f16* __restrict__ d6,
    const float* __restrict__ eb1, float* __restrict__ eb1x)
{
    int q = blockIdx.x * 256 + threadIdx.x;
    if (q >= 852224) return;
    if (q < 524288) {
        const float4 v = *(const float4*)&s0[(size_t)q * 4];
        f16x4 o; o[0]=(f16)v.x; o[1]=(f16)v.y; o[2]=(f16)v.z; o[3]=(f16)v.w;
        int row = q >> 5, col = (q & 31) << 2;
        *(f16x4*)&xcat[(size_t)row * 640 + col] = o;
        return;
    }
    if (q >= 851968) {
        int i = q - 851968;
        int srcq = (i < 128) ? i : i - 128;
        const float4 v = *(const float4*)&eb1[srcq * 4];
        float4 o; o.x = 0.5f*v.x; o.y = 0.5f*v.y; o.z = 0.5f*v.z; o.w = 0.5f*v.w;
        *(float4*)&eb1x[i * 4] = o;
        return;
    }
    if (q < 557056) {
        int i = q - 524288;
        int f = i << 2;
        int n = f >> 8, c = f & 255;
        const float4 v = *(const float4*)&s1[(size_t)f];
        f16x4 o; o[0]=(f16)v.x; o[1]=(f16)v.y; o[2]=(f16)v.z; o[3]=(f16)v.w;
        int dst = (c < 128) ? n * 128 + c : (512 + n) * 128 + (c - 128);
        *(f16x4*)&d1[dst] = o;
        return;
    }
    const float* s; f16* d; int i;
    if      (q < 622592) { s = s2; d = d2; i = q - 557056; }
    else if (q < 688128) { s = s3; d = d3; i = q - 622592; }
    else if (q < 770048) { s = s4; d = d4; i = q - 688128; }
    else if (q < 835584) { s = s5; d = d5; i = q - 770048; }
    else                 { s = s6; d = d6; i = q - 835584; }
    const float4 v = *(const float4*)&s[(size_t)i * 4];
    f16x4 o; o[0]=(f16)v.x; o[1]=(f16)v.y; o[2]=(f16)v.z; o[3]=(f16)v.w;
    *(f16x4*)&d[(size_t)i * 4] = o;
}

// ---------------------------------------------------------------------------
// out[b,:] = (sum_n x3[b,n,:]) @ head_w^T + head_b
// ---------------------------------------------------------------------------
__global__ void head_kernel(const f16* __restrict__ x3, const float* __restrict__ hw,
                            const float* __restrict__ hb, float* __restrict__ out)
{
    __shared__ float pooled[128];
    int b = blockIdx.x, t = threadIdx.x;   // 128 threads
    float s = 0.f;
#pragma unroll
    for (int n = 0; n < 8; ++n) s += (float)x3[(((size_t)b * 8 + n) << 7) + t];
    pooled[t] = s;
    __syncthreads();
    if (t < 12) {
        float acc = hb[t];
        for (int d = 0; d < 128; ++d) acc += pooled[d] * hw[t * 128 + d];
        out[b * 12 + t] = acc;
    }
}

// ---------------------------------------------------------------------------
extern "C" void kernel_launch(void* const* d_in, const int* in_sizes, int n_in,
                              void* d_out, int out_size, void* d_ws, size_t ws_size,
                              hipStream_t stream)
{
    const float* slots  = (const float*)d_in[0];
    const float* ew1    = (const float*)d_in[1];
    const float* eb1    = (const float*)d_in[2];
    const float* ew2    = (const float*)d_in[3];
    const float* eb2    = (const float*)d_in[4];
    const float* eln_g  = (const float*)d_in[5];
    const float* eln_b  = (const float*)d_in[6];
    const float* ew3    = (const float*)d_in[7];
    const float* eb3    = (const float*)d_in[8];
    const float* nw1    = (const float*)d_in[9];
    const float* nb1    = (const float*)d_in[10];
    const float* nw2    = (const float*)d_in[11];
    const float* nb2    = (const float*)d_in[12];
    const float* nln_g  = (const float*)d_in[13];
    const float* nln_b  = (const float*)d_in[14];
    const float* nw3    = (const float*)d_in[15];
    const float* nb3    = (const float*)d_in[16];
    const float* head_w = (const float*)d_in[17];
    const float* head_b = (const float*)d_in[18];

    char* ws = (char*)d_ws;
    f16*   XCAT    = (f16*)(ws + 0);            // 20,971,520
    f16*   w_ew1x  = (f16*)(ws + 20971520);     //   262,144  [1024][128]
    f16*   w_ew2   = (f16*)(ws + 21233664);     //   524,288
    f16*   w_ew3   = (f16*)(ws + 21757952);     //   524,288
    f16*   w_nw1   = (f16*)(ws + 22282240);     //   655,360
    f16*   w_nw2   = (f16*)(ws + 22937600);     //   524,288
    f16*   w_nw3   = (f16*)(ws + 23461888);     //   131,072
    float* eb1x    = (float*)(ws + 23592960);   //     4,096  [1024] f32
    f16*   AGG     = (f16*)(ws + 23597056);     // 16,777,216
    char*  arena   =        ws + 40374272;      // PQc: 33,554,432 (total 74MB)

    f16* PQc = (f16*)(arena);                   // [16384][1024] f16
    f16* X1  = AGG;                             // AGG dead after ew3-GEMM
    f16* X2  = (f16*)(arena);                   // PQc dead after edge kernel
    f16* X3  = (f16*)(arena + 16777216);
    float* out = (float*)d_out;

    convert_all_kernel<<<dim3(3329), 256, 0, stream>>>(
        slots, XCAT, ew1, w_ew1x, ew2, w_ew2, ew3, w_ew3,
        nw1, w_nw1, nw2, w_nw2, nw3, w_nw3, eb1, eb1x);

    // PQ = slots @ [ew1_P; ew1_Q]^T + 0.5*[eb1;eb1]   (one N=1024 GEMM)
    gemm_swz_kernel<false><<<dim3(4, 128), 256, 0, stream>>>(
        XCAT, 640, w_ew1x, 128, eb1x, 1.0f, PQc, 1024, 128);

    // AGG = segsum(relu(LN(relu(P+Q) @ ew2^T + eb2)))   -- E2 never materialized
    edge_ln_agg_kernel<<<dim3(1024), 512, 0, stream>>>(
        PQc, w_ew2, eb2, eln_g, eln_b, AGG);

    // xcat[:,128:640] = AGG @ ew3^T + 7*eb3   (linearity of segment-sum)
    gemm_swz_kernel<false><<<dim3(2, 128), 256, 0, stream>>>(
        AGG, 512, w_ew3, 512, eb3, 7.0f, XCAT + 128, 640, 512);
    // x1 = relu(xcat @ nw1^T + nb1)
    gemm_swz_kernel<true><<<dim3(2, 128), 256, 0, stream>>>(
        XCAT, 640, w_nw1, 640, nb1, 1.0f, X1, 512, 640);
    // x2 = relu(LN(x1 @ nw2^T + nb2))
    fused_gemm_ln<<<dim3(256), 512, 0, stream>>>(
        X1, 512, w_nw2, nb2, nln_g, nln_b, X2, 512);
    // x3 = relu(x2 @ nw3^T + nb3)
    gemm_kernel<true,true><<<dim3(1, 128), 256, 0, stream>>>(
        X2, 512, w_nw3, 512, nb3, 1.0f, X3, 128, 512);

    head_kernel<<<dim3(2048), 128, 0, stream>>>(X3, head_w, head_b, out);
}

// Round 16
// 220.308 us; speedup vs baseline: 1.1238x; 1.1238x over previous
//
#include <hip/hip_runtime.h>
#include <cstdint>
#include <cstddef>

typedef _Float16 f16;
typedef _Float16 f16x8 __attribute__((ext_vector_type(8)));
typedef _Float16 f16x4 __attribute__((ext_vector_type(4)));
typedef float f32x4 __attribute__((ext_vector_type(4)));

#define AS1 __attribute__((address_space(1)))
#define AS3 __attribute__((address_space(3)))

__device__ __forceinline__ void gl_lds16(const void* g, void* l) {
    __builtin_amdgcn_global_load_lds((const AS1 uint32_t*)g, (AS3 uint32_t*)l, 16, 0, 0);
}

__device__ __forceinline__ f16x8 relu8(f16x8 x) {
    f16x8 z = {};
    return __builtin_elementwise_max(x, z);
}

// ===========================================================================
// XOR-slot swizzle (verified r9-r13: SQ_LDS_BANK_CONFLICT~0, coalesced):
//   LDS row-major [ROWS][32] f16; row r's global chunk c at slot c^((r>>1)&3).
//   Staging thread t: row=t>>2, fetches chunk (t&3)^((t>>3)&3).
// ===========================================================================

// ---------------------------------------------------------------------------
// FUSED edge GEMM2 (r13 verified, 93us/643TF): E2 = relu(P[src]+Q[tgt])@ew2^T
// + eb2. PQ[node][1024] (P 0:512, Q 512:1024; 0.5*eb1 folded). 128x256 tile,
// BK=32, 4 waves, 2-buffer + counted vmcnt. A-tile: <=32 node rows staged as
// PQl[2][2048] (coalesced); af = relu8(p+q) from per-lane ds_read_b128.
// ---------------------------------------------------------------------------
__global__ __launch_bounds__(256, 2)
void edge_gemm_fused(const f16* __restrict__ PQ, const f16* __restrict__ W,
                     const float* __restrict__ bias, f16* __restrict__ C)
{
    __shared__ f16 Bs[2][8192];     // [buf][256 rows][32]
    __shared__ f16 PQl[2][2048];    // [buf][ P[32][32] ; Q[32][32] ]
    const int tid  = threadIdx.x;
    const int wave = tid >> 6, lane = tid & 63;
    const int wm = wave >> 1, wn = wave & 1;
    const int lr = lane & 15, lk = lane >> 4;
    const int row0 = blockIdx.y << 7;     // edge row base
    const int col0 = blockIdx.x << 8;

    const int sc16 = (((tid & 3) ^ ((tid >> 3) & 3)) << 3);
    const f16* Wg = W + (size_t)(col0 + (tid >> 2)) * 512 + sc16;
    const int b0 = row0 / 56;
    const int n0 = b0 << 3;
    const f16* PQg = PQ + (size_t)(n0 + ((tid & 127) >> 2)) * 1024
                   + ((tid >> 7) << 9) + sc16;

    // per-lane A-fragment addresses (f16 units into PQl[buf])
    int addrP[4], addrQ[4];
#pragma unroll
    for (int i = 0; i < 4; ++i) {
        int row = wm * 64 + i * 16 + lr;
        int er  = row0 + row;
        int bb  = er / 56;
        int e   = er - bb * 56;
        int r   = e / 7;
        int t2  = e - r * 7;
        int cn  = t2 + (t2 >= r ? 1 : 0);
        int pr  = ((bb - b0) << 3) + r;
        int qr  = ((bb - b0) << 3) + cn;
        addrP[i] = pr * 32 + ((lk ^ ((pr >> 1) & 3)) << 3);
        addrQ[i] = 1024 + qr * 32 + ((lk ^ ((qr >> 1) & 3)) << 3);
    }
    const int kx = (lk ^ ((lr >> 1) & 3)) << 3;   // B read slot

    f32x4 acc[4][8] = {};

#define STAGE(buf, k0)                                                        \
    do {                                                                      \
        gl_lds16(PQg + (k0), &PQl[buf][tid * 8]);                             \
        _Pragma("unroll")                                                     \
        for (int i_ = 0; i_ < 4; ++i_)                                        \
            gl_lds16(Wg + (k0) + (size_t)(i_ * 64) * 512,                     \
                     &Bs[buf][(i_ * 256 + tid) * 8]);                         \
    } while (0)

    STAGE(0, 0);                              // 5 loads in flight
    for (int t = 0; t < 16; ++t) {
        const int cur = t & 1;
        if (t < 15) {
            STAGE(cur ^ 1, (t + 1) << 5);     // +5 loads (tile t+1)
            asm volatile("s_waitcnt vmcnt(5)" ::: "memory");  // tile t landed
        } else {
            asm volatile("s_waitcnt vmcnt(0)" ::: "memory");
        }
        __builtin_amdgcn_s_barrier();
        __builtin_amdgcn_sched_barrier(0);

        f16x8 af[4], bf[8];
#pragma unroll
        for (int i = 0; i < 4; ++i) {
            f16x8 p = *(const f16x8*)&PQl[cur][addrP[i]];
            f16x8 q = *(const f16x8*)&PQl[cur][addrQ[i]];
            af[i] = relu8(p + q);
        }
#pragma unroll
        for (int i = 0; i < 8; ++i)
            bf[i] = *(const f16x8*)&Bs[cur][(wn * 128 + i * 16 + lr) * 32 + kx];
#pragma unroll
        for (int mi = 0; mi < 4; ++mi)
#pragma unroll
            for (int ni = 0; ni < 8; ++ni)
                acc[mi][ni] = __builtin_amdgcn_mfma_f32_16x16x32_f16(
                    af[mi], bf[ni], acc[mi][ni], 0, 0, 0);

        __builtin_amdgcn_sched_barrier(0);
        __builtin_amdgcn_s_barrier();
    }
#undef STAGE

#pragma unroll
    for (int mi = 0; mi < 4; ++mi) {
#pragma unroll
        for (int ni = 0; ni < 8; ++ni) {
#pragma unroll
            for (int j = 0; j < 4; ++j) {
                int r = row0 + wm * 64 + mi * 16 + lk * 4 + j;
                int c = col0 + wn * 128 + ni * 16 + lr;
                C[(size_t)r * 512 + c] = (f16)(acc[mi][ni][j] + bias[c]);
            }
        }
    }
}

// ===========================================================================
// XOR-slot swizzled 128x256 GEMM (r10/r11 verified). Used for PQ (K=128),
// ew3, nw1. launch_bounds MUST stay (256,2): (256,4) spills acc (r9).
// ===========================================================================
template<bool RELU>
__global__ __launch_bounds__(256, 2)
void gemm_swz_kernel(const f16* __restrict__ A, int lda,
                     const f16* __restrict__ W, int ldw,
                     const float* __restrict__ bias, float bscale,
                     f16* __restrict__ C, int ldc, int K)
{
    __shared__ f16 As[2][4096];
    __shared__ f16 Bs[2][8192];
    const int tid  = threadIdx.x;
    const int wave = tid >> 6, lane = tid & 63;
    const int wm = wave >> 1, wn = wave & 1;
    const int lr = lane & 15, lk = lane >> 4;
    const int row0 = blockIdx.y << 7;
    const int col0 = blockIdx.x << 8;

    const int c16 = (((tid & 3) ^ ((tid >> 3) & 3)) << 3);
    const f16* Ag = A + (size_t)(row0 + (tid >> 2)) * lda + c16;
    const f16* Wg = W + (size_t)(col0 + (tid >> 2)) * ldw + c16;
    const int kx = (lk ^ ((lr >> 1) & 3)) << 3;

    f32x4 acc[4][8] = {};

#define STAGE(buf, k0)                                                        \
    do {                                                                      \
        gl_lds16(Ag + (k0),                      &As[buf][tid * 8]);          \
        gl_lds16(Ag + (k0) + (size_t)64 * lda,   &As[buf][(tid + 256) * 8]);  \
        _Pragma("unroll")                                                     \
        for (int i_ = 0; i_ < 4; ++i_)                                        \
            gl_lds16(Wg + (k0) + (size_t)(i_ * 64) * ldw,                     \
                     &Bs[buf][(i_ * 256 + tid) * 8]);                         \
    } while (0)

    const int nt = K >> 5;
    STAGE(0, 0);
    for (int t = 0; t < nt; ++t) {
        const int cur = t & 1;
        if (t + 1 < nt) {
            STAGE(cur ^ 1, (t + 1) << 5);
            asm volatile("s_waitcnt vmcnt(6)" ::: "memory");
        } else {
            asm volatile("s_waitcnt vmcnt(0)" ::: "memory");
        }
        __builtin_amdgcn_s_barrier();
        __builtin_amdgcn_sched_barrier(0);

        f16x8 af[4], bf[8];
#pragma unroll
        for (int i = 0; i < 4; ++i)
            af[i] = *(const f16x8*)&As[cur][(wm * 64 + i * 16 + lr) * 32 + kx];
#pragma unroll
        for (int i = 0; i < 8; ++i)
            bf[i] = *(const f16x8*)&Bs[cur][(wn * 128 + i * 16 + lr) * 32 + kx];
#pragma unroll
        for (int mi = 0; mi < 4; ++mi)
#pragma unroll
            for (int ni = 0; ni < 8; ++ni)
                acc[mi][ni] = __builtin_amdgcn_mfma_f32_16x16x32_f16(
                    af[mi], bf[ni], acc[mi][ni], 0, 0, 0);

        __builtin_amdgcn_sched_barrier(0);
        __builtin_amdgcn_s_barrier();
    }
#undef STAGE

#pragma unroll
    for (int mi = 0; mi < 4; ++mi) {
#pragma unroll
        for (int ni = 0; ni < 8; ++ni) {
#pragma unroll
            for (int j = 0; j < 4; ++j) {
                int r = row0 + wm * 64 + mi * 16 + lk * 4 + j;
                int c = col0 + wn * 128 + ni * 16 + lr;
                float v = acc[mi][ni][j] + bias[c] * bscale;
                if (RELU) v = fmaxf(v, 0.0f);
                C[(size_t)r * ldc + c] = (f16)v;
            }
        }
    }
}

// ---------------------------------------------------------------------------
// Small GEMM (N=128; used once for nw3): 128x128 tile, legacy layout.
// ---------------------------------------------------------------------------
template<bool BIAS, bool RELU>
__global__ __launch_bounds__(256, 2)
void gemm_kernel(const f16* __restrict__ A, int lda,
                 const f16* __restrict__ W, int ldw,
                 const float* __restrict__ bias, float bscale,
                 f16* __restrict__ C, int ldc, int K)
{
    __shared__ f16 As[4096];
    __shared__ f16 Bs[4096];
    const int tid  = threadIdx.x;
    const int wave = tid >> 6;
    const int lane = tid & 63;
    const int wm = wave >> 1, wn = wave & 1;
    const int lr = lane & 15, lk = lane >> 4;
    const int row0 = blockIdx.y << 7;
    const int col0 = blockIdx.x << 7;

    const int srow = tid >> 2;
    const int scol = (tid & 3) << 3;
    const f16* Ag = A + (size_t)(row0 + srow) * lda + scol;
    const f16* Wg = W + (size_t)(col0 + srow) * ldw + scol;
    f16* lA0 = &As[wave * 512];
    f16* lA1 = &As[2048 + wave * 512];
    f16* lB0 = &Bs[wave * 512];
    f16* lB1 = &Bs[2048 + wave * 512];

    f32x4 acc[4][4] = {};

    for (int k0 = 0; k0 < K; k0 += 32) {
        if (k0) __syncthreads();
        gl_lds16(Ag + k0,                    lA0);
        gl_lds16(Ag + k0 + (size_t)64 * lda, lA1);
        gl_lds16(Wg + k0,                    lB0);
        gl_lds16(Wg + k0 + (size_t)64 * ldw, lB1);
        __syncthreads();

        f16x8 af[4], bf[4];
#pragma unroll
        for (int i = 0; i < 4; ++i)
            af[i] = *(const f16x8*)&As[(wm * 64 + i * 16 + lr) * 32 + lk * 8];
#pragma unroll
        for (int i = 0; i < 4; ++i)
            bf[i] = *(const f16x8*)&Bs[(wn * 64 + i * 16 + lr) * 32 + lk * 8];
#pragma unroll
        for (int mi = 0; mi < 4; ++mi)
#pragma unroll
            for (int ni = 0; ni < 4; ++ni)
                acc[mi][ni] = __builtin_amdgcn_mfma_f32_16x16x32_f16(
                    af[mi], bf[ni], acc[mi][ni], 0, 0, 0);
    }

#pragma unroll
    for (int mi = 0; mi < 4; ++mi) {
#pragma unroll
        for (int ni = 0; ni < 4; ++ni) {
#pragma unroll
            for (int j = 0; j < 4; ++j) {
                int r = row0 + wm * 64 + mi * 16 + lk * 4 + j;
                int c = col0 + wn * 64 + ni * 16 + lr;
                float v = acc[mi][ni][j];
                if (BIAS) v += bias[c] * bscale;
                if (RELU) v = fmaxf(v, 0.0f);
                C[(size_t)r * ldc + c] = (f16)v;
            }
        }
    }
}

// ---------------------------------------------------------------------------
// Fused GEMM + bias + LayerNorm + relu (node MLP layer 2). BM=64, 8 waves,
// K=512, W row-stride 512. XOR-slot swizzled staging (coalesced).
// ---------------------------------------------------------------------------
__global__ __launch_bounds__(512, 2)
void fused_gemm_ln(const f16* __restrict__ A, int lda,
                   const f16* __restrict__ W,
                   const float* __restrict__ bias,
                   const float* __restrict__ g, const float* __restrict__ b,
                   f16* __restrict__ C, int ldc)
{
    constexpr int BM = 64, NI = 4, NWN = 8;
    __shared__ f16 As[BM * 32];
    __shared__ f16 Bs[512 * 32];
    __shared__ float lnred[BM * NWN * 2];
    __shared__ float stat[BM * 2];

    const int tid  = threadIdx.x;
    const int wave = tid >> 6;
    const int lane = tid & 63;
    const int wn = wave;
    const int lr = lane & 15, lk = lane >> 4;
    const int row0 = blockIdx.x * BM;
    const int wcol0 = wn * (NI * 16);

    const int c16 = (((tid & 3) ^ ((tid >> 3) & 3)) << 3);
    const f16* Ar = A + (size_t)(row0 + (tid >> 2)) * lda + c16;
    const f16* Wr = W + (size_t)(tid >> 2) * 512 + c16;
    const int kx = (lk ^ ((lr >> 1) & 3)) << 3;

    f32x4 acc[4][NI] = {};

    for (int k0 = 0; k0 < 512; k0 += 32) {
        if (k0) __syncthreads();
#pragma unroll
        for (int i = 0; i < 4; ++i)
            gl_lds16(Wr + k0 + (size_t)(i * 128) * 512, &Bs[(i * 512 + tid) * 8]);
        if (tid < 256)
            gl_lds16(Ar + k0, &As[tid * 8]);
        __syncthreads();

        f16x8 af[4], bf[NI];
#pragma unroll
        for (int i = 0; i < 4; ++i)
            af[i] = *(const f16x8*)&As[(i * 16 + lr) * 32 + kx];
#pragma unroll
        for (int i = 0; i < NI; ++i)
            bf[i] = *(const f16x8*)&Bs[(wcol0 + i * 16 + lr) * 32 + kx];
#pragma unroll
        for (int mi = 0; mi < 4; ++mi)
#pragma unroll
            for (int ni = 0; ni < NI; ++ni)
                acc[mi][ni] = __builtin_amdgcn_mfma_f32_16x16x32_f16(
                    af[mi], bf[ni], acc[mi][ni], 0, 0, 0);
    }

    float biasv[NI], gv[NI], bv[NI];
#pragma unroll
    for (int ni = 0; ni < NI; ++ni) {
        int col = wcol0 + ni * 16 + lr;
        biasv[ni] = bias[col];
        gv[ni] = g[col];
        bv[ni] = b[col];
    }
#pragma unroll
    for (int mi = 0; mi < 4; ++mi)
#pragma unroll
        for (int ni = 0; ni < NI; ++ni)
#pragma unroll
            for (int j = 0; j < 4; ++j)
                acc[mi][ni][j] += biasv[ni];

#pragma unroll
    for (int mi = 0; mi < 4; ++mi) {
#pragma unroll
        for (int j = 0; j < 4; ++j) {
            float s = 0.f, s2 = 0.f;
#pragma unroll
            for (int ni = 0; ni < NI; ++ni) {
                float v = acc[mi][ni][j];
                s += v; s2 += v * v;
            }
#pragma unroll
            for (int o = 1; o < 16; o <<= 1) {
                s  += __shfl_xor(s,  o, 64);
                s2 += __shfl_xor(s2, o, 64);
            }
            if (lr == 0) {
                int row = mi * 16 + lk * 4 + j;
                lnred[(row * NWN + wn) * 2 + 0] = s;
                lnred[(row * NWN + wn) * 2 + 1] = s2;
            }
        }
    }
    __syncthreads();
    if (tid < BM) {
        float s = 0.f, s2 = 0.f;
#pragma unroll
        for (int w = 0; w < NWN; ++w) {
            s  += lnred[(tid * NWN + w) * 2 + 0];
            s2 += lnred[(tid * NWN + w) * 2 + 1];
        }
        float mean = s * (1.0f / 512.0f);
        float var  = fmaxf(s2 * (1.0f / 512.0f) - mean * mean, 0.0f);
        stat[tid * 2 + 0] = mean;
        stat[tid * 2 + 1] = rsqrtf(var + 1e-5f);
    }
    __syncthreads();

#pragma unroll
    for (int mi = 0; mi < 4; ++mi) {
#pragma unroll
        for (int j = 0; j < 4; ++j) {
            int row = mi * 16 + lk * 4 + j;
            float mean = stat[row * 2 + 0];
            float rstd = stat[row * 2 + 1];
            size_t gr = (size_t)(row0 + row) * ldc;
#pragma unroll
            for (int ni = 0; ni < NI; ++ni) {
                float y = (acc[mi][ni][j] - mean) * rstd * gv[ni] + bv[ni];
                C[gr + wcol0 + ni * 16 + lr] = (f16)fmaxf(y, 0.0f);
            }
        }
    }
}

// ---------------------------------------------------------------------------
// Convert fp32 -> f16. Slots strided into XCAT cols 0:128 (ldc=640).
// ew1 repacked: w_ew1x[1024][128] = [ew1[:, :128] ; ew1[:, 128:]].
// eb1x[1024] f32 = 0.5*[eb1 ; eb1].
// ---------------------------------------------------------------------------
__global__ void convert_all_kernel(
    const float* __restrict__ s0, f16* __restrict__ xcat,
    const float* __restrict__ s1, f16* __restrict__ d1,
    const float* __restrict__ s2, f16* __restrict__ d2,
    const float* __restrict__ s3, f16* __restrict__ d3,
    const float* __restrict__ s4, f16* __restrict__ d4,
    const float* __restrict__ s5, f16* __restrict__ d5,
    const float* __restrict__ s6, f16* __restrict__ d6,
    const float* __restrict__ eb1, float* __restrict__ eb1x)
{
    int q = blockIdx.x * 256 + threadIdx.x;
    if (q >= 852224) return;
    if (q < 524288) {
        const float4 v = *(const float4*)&s0[(size_t)q * 4];
        f16x4 o; o[0]=(f16)v.x; o[1]=(f16)v.y; o[2]=(f16)v.z; o[3]=(f16)v.w;
        int row = q >> 5, col = (q & 31) << 2;
        *(f16x4*)&xcat[(size_t)row * 640 + col] = o;
        return;
    }
    if (q >= 851968) {
        int i = q - 851968;
        int srcq = (i < 128) ? i : i - 128;
        const float4 v = *(const float4*)&eb1[srcq * 4];
        float4 o; o.x = 0.5f*v.x; o.y = 0.5f*v.y; o.z = 0.5f*v.z; o.w = 0.5f*v.w;
        *(float4*)&eb1x[i * 4] = o;
        return;
    }
    if (q < 557056) {
        int i = q - 524288;
        int f = i << 2;
        int n = f >> 8, c = f & 255;
        const float4 v = *(const float4*)&s1[(size_t)f];
        f16x4 o; o[0]=(f16)v.x; o[1]=(f16)v.y; o[2]=(f16)v.z; o[3]=(f16)v.w;
        int dst = (c < 128) ? n * 128 + c : (512 + n) * 128 + (c - 128);
        *(f16x4*)&d1[dst] = o;
        return;
    }
    const float* s; f16* d; int i;
    if      (q < 622592) { s = s2; d = d2; i = q - 557056; }
    else if (q < 688128) { s = s3; d = d3; i = q - 622592; }
    else if (q < 770048) { s = s4; d = d4; i = q - 688128; }
    else if (q < 835584) { s = s5; d = d5; i = q - 770048; }
    else                 { s = s6; d = d6; i = q - 835584; }
    const float4 v = *(const float4*)&s[(size_t)i * 4];
    f16x4 o; o[0]=(f16)v.x; o[1]=(f16)v.y; o[2]=(f16)v.z; o[3]=(f16)v.w;
    *(f16x4*)&d[(size_t)i * 4] = o;
}

// ---------------------------------------------------------------------------
// ln_agg: AGG[node,:] = sum_{t<7} relu(LN(E2[node*7+t,:])*g+b). 1 wave/node.
// ---------------------------------------------------------------------------
__global__ void ln_agg_kernel(const f16* __restrict__ E2,
                              const float* __restrict__ g, const float* __restrict__ b,
                              f16* __restrict__ AGG, int nodes)
{
    int gw   = (blockIdx.x * 256 + threadIdx.x) >> 6;
    int lane = threadIdx.x & 63;
    if (gw >= nodes) return;
    int bb = gw >> 3, n = gw & 7;
    const f16* base = E2 + (((size_t)(bb * 56 + n * 7)) << 9) + (lane << 3);
    f16x8 v[7];
#pragma unroll
    for (int t = 0; t < 7; ++t) v[t] = *(const f16x8*)(base + ((size_t)t << 9));
    float gv[8], bv[8], acc[8] = {};
#pragma unroll
    for (int j = 0; j < 8; ++j) {
        gv[j] = g[(lane << 3) + j];
        bv[j] = b[(lane << 3) + j];
    }
#pragma unroll
    for (int t = 0; t < 7; ++t) {
        float f[8]; float s = 0.f, s2 = 0.f;
#pragma unroll
        for (int j = 0; j < 8; ++j) { f[j] = (float)v[t][j]; s += f[j]; s2 += f[j] * f[j]; }
#pragma unroll
        for (int o = 32; o; o >>= 1) { s += __shfl_xor(s, o, 64); s2 += __shfl_xor(s2, o, 64); }
        float mean = s * (1.0f / 512.0f);
        float var  = fmaxf(s2 * (1.0f / 512.0f) - mean * mean, 0.0f);
        float rstd = rsqrtf(var + 1e-5f);
#pragma unroll
        for (int j = 0; j < 8; ++j)
            acc[j] += fmaxf((f[j] - mean) * rstd * gv[j] + bv[j], 0.0f);
    }
    f16x8 o;
#pragma unroll
    for (int j = 0; j < 8; ++j) o[j] = (f16)acc[j];
    *(f16x8*)&AGG[((size_t)gw << 9) + (lane << 3)] = o;
}

// ---------------------------------------------------------------------------
// out[b,:] = (sum_n x3[b,n,:]) @ head_w^T + head_b
// ---------------------------------------------------------------------------
__global__ void head_kernel(const f16* __restrict__ x3, const float* __restrict__ hw,
                            const float* __restrict__ hb, float* __restrict__ out)
{
    __shared__ float pooled[128];
    int b = blockIdx.x, t = threadIdx.x;   // 128 threads
    float s = 0.f;
#pragma unroll
    for (int n = 0; n < 8; ++n) s += (float)x3[(((size_t)b * 8 + n) << 7) + t];
    pooled[t] = s;
    __syncthreads();
    if (t < 12) {
        float acc = hb[t];
        for (int d = 0; d < 128; ++d) acc += pooled[d] * hw[t * 128 + d];
        out[b * 12 + t] = acc;
    }
}

// ---------------------------------------------------------------------------
extern "C" void kernel_launch(void* const* d_in, const int* in_sizes, int n_in,
                              void* d_out, int out_size, void* d_ws, size_t ws_size,
                              hipStream_t stream)
{
    const float* slots  = (const float*)d_in[0];
    const float* ew1    = (const float*)d_in[1];
    const float* eb1    = (const float*)d_in[2];
    const float* ew2    = (const float*)d_in[3];
    const float* eb2    = (const float*)d_in[4];
    const float* eln_g  = (const float*)d_in[5];
    const float* eln_b  = (const float*)d_in[6];
    const float* ew3    = (const float*)d_in[7];
    const float* eb3    = (const float*)d_in[8];
    const float* nw1    = (const float*)d_in[9];
    const float* nb1    = (const float*)d_in[10];
    const float* nw2    = (const float*)d_in[11];
    const float* nb2    = (const float*)d_in[12];
    const float* nln_g  = (const float*)d_in[13];
    const float* nln_b  = (const float*)d_in[14];
    const float* nw3    = (const float*)d_in[15];
    const float* nb3    = (const float*)d_in[16];
    const float* head_w = (const float*)d_in[17];
    const float* head_b = (const float*)d_in[18];

    char* ws = (char*)d_ws;
    f16*   XCAT    = (f16*)(ws + 0);            // 20,971,520
    f16*   w_ew1x  = (f16*)(ws + 20971520);     //   262,144  [1024][128]
    f16*   w_ew2   = (f16*)(ws + 21233664);     //   524,288
    f16*   w_ew3   = (f16*)(ws + 21757952);     //   524,288
    f16*   w_nw1   = (f16*)(ws + 22282240);     //   655,360
    f16*   w_nw2   = (f16*)(ws + 22937600);     //   524,288
    f16*   w_nw3   = (f16*)(ws + 23461888);     //   131,072
    float* eb1x    = (float*)(ws + 23592960);   //     4,096  [1024] f32
    f16*   AGG     = (f16*)(ws + 23597056);     // 16,777,216
    char*  arena   =        ws + 40374272;      // 73728*BCH bytes

    // arena = PQc(16384*BCH) + E2c(57344*BCH)
    const size_t FIXED = 40374272ULL;
    int BCH;
    if      (ws_size >= FIXED + 73728ULL * 2048) BCH = 2048;  // 191.4 MB
    else if (ws_size >= FIXED + 73728ULL * 1024) BCH = 1024;  // 115.9 MB
    else                                         BCH = 512;   //  78.1 MB
    const int nch = 2048 / BCH;
    const int RN  = BCH * 8;    // node rows / chunk
    const int RE  = BCH * 56;   // edge rows / chunk (mult 128)

    f16* PQc = (f16*)(arena);                                  // 16384*BCH B
    f16* E2c = (f16*)(arena + (size_t)16384 * BCH);            // 57344*BCH B

    f16* X1 = AGG;
    f16* X2 = (f16*)(arena);
    f16* X3 = (f16*)(arena + 16777216);
    float* out = (float*)d_out;

    convert_all_kernel<<<dim3(3329), 256, 0, stream>>>(
        slots, XCAT, ew1, w_ew1x, ew2, w_ew2, ew3, w_ew3,
        nw1, w_nw1, nw2, w_nw2, nw3, w_nw3, eb1, eb1x);

    for (int c = 0; c < nch; ++c) {
        const f16* sc = XCAT + (size_t)c * RN * 640;
        // PQ = slots @ [ew1_P; ew1_Q]^T + 0.5*[eb1;eb1]   (one N=1024 GEMM)
        gemm_swz_kernel<false><<<dim3(4, RN/128), 256, 0, stream>>>(
            sc, 640, w_ew1x, 128, eb1x, 1.0f, PQc, 1024, 128);
        // e2 = relu(P[src]+Q[tgt]) @ ew2^T + eb2   (fused; no E1)
        edge_gemm_fused<<<dim3(2, RE/128), 256, 0, stream>>>(
            PQc, w_ew2, eb2, E2c);
        // agg = segsum(relu(LN(e2)))
        ln_agg_kernel<<<dim3(RN/4), 256, 0, stream>>>(
            E2c, eln_g, eln_b, AGG + (size_t)c * RN * 512, RN);
    }

    // xcat[:,128:640] = AGG @ ew3^T + 7*eb3   (linearity of segment-sum)
    gemm_swz_kernel<false><<<dim3(2,128), 256, 0, stream>>>(
        AGG, 512, w_ew3, 512, eb3, 7.0f, XCAT + 128, 640, 512);
    // x1 = relu(xcat @ nw1^T + nb1)
    gemm_swz_kernel<true><<<dim3(2,128), 256, 0, stream>>>(
        XCAT, 640, w_nw1, 640, nb1, 1.0f, X1, 512, 640);
    // x2 = relu(LN(x1 @ nw2^T + nb2))
    fused_gemm_ln<<<dim3(256), 512, 0, stream>>>(
        X1, 512, w_nw2, nb2, nln_g, nln_b, X2, 512);
    // x3 = relu(x2 @ nw3^T + nb3)
    gemm_kernel<true,true><<<dim3(1,128), 256, 0, stream>>>(
        X2, 512, w_nw3, 512, nb3, 1.0f, X3, 128, 512);

    head_kernel<<<dim3(2048), 128, 0, stream>>>(X3, head_w, head_b, out);
}

// Round 17
// 212.393 us; speedup vs baseline: 1.1657x; 1.0373x over previous
//
#include <hip/hip_runtime.h>
#include <cstdint>
#include <cstddef>

typedef _Float16 f16;
typedef _Float16 f16x8 __attribute__((ext_vector_type(8)));
typedef _Float16 f16x4 __attribute__((ext_vector_type(4)));
typedef float f32x4 __attribute__((ext_vector_type(4)));

#define AS1 __attribute__((address_space(1)))
#define AS3 __attribute__((address_space(3)))

__device__ __forceinline__ void gl_lds16(const void* g, void* l) {
    __builtin_amdgcn_global_load_lds((const AS1 uint32_t*)g, (AS3 uint32_t*)l, 16, 0, 0);
}

__device__ __forceinline__ f16x8 relu8(f16x8 x) {
    f16x8 z = {};
    return __builtin_elementwise_max(x, z);
}

// ---------------------------------------------------------------------------
// FUSED edge GEMM2, BK=64 variant: E2 = relu(P[src]+Q[tgt]) @ ew2^T + eb2.
// 128x256 tile, 4 waves (2x2, wave 64x128), 2 LDS buffers, counted vmcnt.
// BK=64 halves barrier-drain events (16 -> 8 K-tiles) at same per-K work;
// LDS 80KB keeps 2 blocks/CU (the m132 BK-too-big failure was occupancy).
// [row][64] layout, slot swizzle s = c^(r&7): balanced 8 lanes/slot ->
// minimum-cycle b128 reads; staging source permuted within each row's 128B
// (coalesced); gl_lds dest lane-linear. kk-pass (K=32 halves) = addr ^ 32.
// ---------------------------------------------------------------------------
__global__ __launch_bounds__(256, 2)
void edge_gemm_fused(const f16* __restrict__ PQ, const f16* __restrict__ W,
                     const float* __restrict__ bias, f16* __restrict__ C)
{
    __shared__ f16 Bs[2][16384];    // [buf][256 rows][64]
    __shared__ f16 PQl[2][4096];    // [buf][ P[32][64] ; Q[32][64] ]
    const int tid  = threadIdx.x;
    const int wave = tid >> 6, lane = tid & 63;
    const int wm = wave >> 1, wn = wave & 1;
    const int lr = lane & 15, lk = lane >> 4;
    const int row0 = blockIdx.y << 7;     // edge row base
    const int col0 = blockIdx.x << 8;

    // staging: thread t -> row (t>>3), source chunk (t&7)^((t>>3)&7)
    const int sc8 = (((tid & 7) ^ ((tid >> 3) & 7)) << 3);
    const f16* Wg  = W + (size_t)(col0 + (tid >> 3)) * 512 + sc8;
    const int b0 = row0 / 56;
    const int n0 = b0 << 3;
    const f16* PQg = PQ + (size_t)(n0 + (tid >> 3)) * 1024 + sc8;

    // per-lane A-fragment addresses (f16 units; kk=1 pass = addr ^ 32)
    int addrP[4], addrQ[4];
#pragma unroll
    for (int i = 0; i < 4; ++i) {
        int row = wm * 64 + i * 16 + lr;
        int er  = row0 + row;
        int bb  = er / 56;
        int e   = er - bb * 56;
        int r   = e / 7;
        int t2  = e - r * 7;
        int cn  = t2 + (t2 >= r ? 1 : 0);
        int pr  = ((bb - b0) << 3) + r;
        int qr  = ((bb - b0) << 3) + cn;
        addrP[i] = pr * 64 + ((lk ^ (pr & 7)) << 3);
        addrQ[i] = 2048 + qr * 64 + ((lk ^ (qr & 7)) << 3);
    }
    int addrB[8];
#pragma unroll
    for (int i = 0; i < 8; ++i) {
        int row = wn * 128 + i * 16 + lr;
        addrB[i] = row * 64 + ((lk ^ (row & 7)) << 3);
    }

    f32x4 acc[4][8] = {};

#define STAGE(buf, k0)                                                        \
    do {                                                                      \
        _Pragma("unroll")                                                     \
        for (int i_ = 0; i_ < 8; ++i_)                                        \
            gl_lds16(Wg + (k0) + (size_t)(i_ * 32) * 512,                     \
                     &Bs[buf][(i_ * 256 + tid) * 8]);                         \
        gl_lds16(PQg + (k0),       &PQl[buf][tid * 8]);                       \
        gl_lds16(PQg + (k0) + 512, &PQl[buf][2048 + tid * 8]);                \
    } while (0)

    STAGE(0, 0);                              // 10 loads in flight
    for (int t = 0; t < 8; ++t) {
        const int cur = t & 1;
        if (t < 7) {
            STAGE(cur ^ 1, (t + 1) << 6);     // +10 loads (tile t+1)
            asm volatile("s_waitcnt vmcnt(10)" ::: "memory"); // tile t landed
        } else {
            asm volatile("s_waitcnt vmcnt(0)" ::: "memory");
        }
        __builtin_amdgcn_s_barrier();
        __builtin_amdgcn_sched_barrier(0);

#pragma unroll
        for (int kk = 0; kk < 2; ++kk) {
            const int kxor = kk << 5;
            f16x8 af[4], bf[8];
#pragma unroll
            for (int i = 0; i < 4; ++i) {
                f16x8 p = *(const f16x8*)&PQl[cur][addrP[i] ^ kxor];
                f16x8 q = *(const f16x8*)&PQl[cur][addrQ[i] ^ kxor];
                af[i] = relu8(p + q);
            }
#pragma unroll
            for (int i = 0; i < 8; ++i)
                bf[i] = *(const f16x8*)&Bs[cur][addrB[i] ^ kxor];
#pragma unroll
            for (int mi = 0; mi < 4; ++mi)
#pragma unroll
                for (int ni = 0; ni < 8; ++ni)
                    acc[mi][ni] = __builtin_amdgcn_mfma_f32_16x16x32_f16(
                        af[mi], bf[ni], acc[mi][ni], 0, 0, 0);
        }

        __builtin_amdgcn_sched_barrier(0);
        __builtin_amdgcn_s_barrier();         // reads of buf[cur] complete
    }
#undef STAGE

#pragma unroll
    for (int mi = 0; mi < 4; ++mi) {
#pragma unroll
        for (int ni = 0; ni < 8; ++ni) {
#pragma unroll
            for (int j = 0; j < 4; ++j) {
                int r = row0 + wm * 64 + mi * 16 + lk * 4 + j;
                int c = col0 + wn * 128 + ni * 16 + lr;
                C[(size_t)r * 512 + c] = (f16)(acc[mi][ni][j] + bias[c]);
            }
        }
    }
}

// ===========================================================================
// XOR-slot swizzled 128x256 GEMM (r10-r16 verified). PQ (K=128), ew3, nw1.
// launch_bounds MUST stay (256,2): (256,4) spills acc (r9).
// ===========================================================================
template<bool RELU>
__global__ __launch_bounds__(256, 2)
void gemm_swz_kernel(const f16* __restrict__ A, int lda,
                     const f16* __restrict__ W, int ldw,
                     const float* __restrict__ bias, float bscale,
                     f16* __restrict__ C, int ldc, int K)
{
    __shared__ f16 As[2][4096];
    __shared__ f16 Bs[2][8192];
    const int tid  = threadIdx.x;
    const int wave = tid >> 6, lane = tid & 63;
    const int wm = wave >> 1, wn = wave & 1;
    const int lr = lane & 15, lk = lane >> 4;
    const int row0 = blockIdx.y << 7;
    const int col0 = blockIdx.x << 8;

    const int c16 = (((tid & 3) ^ ((tid >> 3) & 3)) << 3);
    const f16* Ag = A + (size_t)(row0 + (tid >> 2)) * lda + c16;
    const f16* Wg = W + (size_t)(col0 + (tid >> 2)) * ldw + c16;
    const int kx = (lk ^ ((lr >> 1) & 3)) << 3;

    f32x4 acc[4][8] = {};

#define STAGE(buf, k0)                                                        \
    do {                                                                      \
        gl_lds16(Ag + (k0),                      &As[buf][tid * 8]);          \
        gl_lds16(Ag + (k0) + (size_t)64 * lda,   &As[buf][(tid + 256) * 8]);  \
        _Pragma("unroll")                                                     \
        for (int i_ = 0; i_ < 4; ++i_)                                        \
            gl_lds16(Wg + (k0) + (size_t)(i_ * 64) * ldw,                     \
                     &Bs[buf][(i_ * 256 + tid) * 8]);                         \
    } while (0)

    const int nt = K >> 5;
    STAGE(0, 0);
    for (int t = 0; t < nt; ++t) {
        const int cur = t & 1;
        if (t + 1 < nt) {
            STAGE(cur ^ 1, (t + 1) << 5);
            asm volatile("s_waitcnt vmcnt(6)" ::: "memory");
        } else {
            asm volatile("s_waitcnt vmcnt(0)" ::: "memory");
        }
        __builtin_amdgcn_s_barrier();
        __builtin_amdgcn_sched_barrier(0);

        f16x8 af[4], bf[8];
#pragma unroll
        for (int i = 0; i < 4; ++i)
            af[i] = *(const f16x8*)&As[cur][(wm * 64 + i * 16 + lr) * 32 + kx];
#pragma unroll
        for (int i = 0; i < 8; ++i)
            bf[i] = *(const f16x8*)&Bs[cur][(wn * 128 + i * 16 + lr) * 32 + kx];
#pragma unroll
        for (int mi = 0; mi < 4; ++mi)
#pragma unroll
            for (int ni = 0; ni < 8; ++ni)
                acc[mi][ni] = __builtin_amdgcn_mfma_f32_16x16x32_f16(
                    af[mi], bf[ni], acc[mi][ni], 0, 0, 0);

        __builtin_amdgcn_sched_barrier(0);
        __builtin_amdgcn_s_barrier();
    }
#undef STAGE

#pragma unroll
    for (int mi = 0; mi < 4; ++mi) {
#pragma unroll
        for (int ni = 0; ni < 8; ++ni) {
#pragma unroll
            for (int j = 0; j < 4; ++j) {
                int r = row0 + wm * 64 + mi * 16 + lk * 4 + j;
                int c = col0 + wn * 128 + ni * 16 + lr;
                float v = acc[mi][ni][j] + bias[c] * bscale;
                if (RELU) v = fmaxf(v, 0.0f);
                C[(size_t)r * ldc + c] = (f16)v;
            }
        }
    }
}

// ---------------------------------------------------------------------------
// Small GEMM (N=128; used once for nw3): 128x128 tile, legacy layout.
// ---------------------------------------------------------------------------
template<bool BIAS, bool RELU>
__global__ __launch_bounds__(256, 2)
void gemm_kernel(const f16* __restrict__ A, int lda,
                 const f16* __restrict__ W, int ldw,
                 const float* __restrict__ bias, float bscale,
                 f16* __restrict__ C, int ldc, int K)
{
    __shared__ f16 As[4096];
    __shared__ f16 Bs[4096];
    const int tid  = threadIdx.x;
    const int wave = tid >> 6;
    const int lane = tid & 63;
    const int wm = wave >> 1, wn = wave & 1;
    const int lr = lane & 15, lk = lane >> 4;
    const int row0 = blockIdx.y << 7;
    const int col0 = blockIdx.x << 7;

    const int srow = tid >> 2;
    const int scol = (tid & 3) << 3;
    const f16* Ag = A + (size_t)(row0 + srow) * lda + scol;
    const f16* Wg = W + (size_t)(col0 + srow) * ldw + scol;
    f16* lA0 = &As[wave * 512];
    f16* lA1 = &As[2048 + wave * 512];
    f16* lB0 = &Bs[wave * 512];
    f16* lB1 = &Bs[2048 + wave * 512];

    f32x4 acc[4][4] = {};

    for (int k0 = 0; k0 < K; k0 += 32) {
        if (k0) __syncthreads();
        gl_lds16(Ag + k0,                    lA0);
        gl_lds16(Ag + k0 + (size_t)64 * lda, lA1);
        gl_lds16(Wg + k0,                    lB0);
        gl_lds16(Wg + k0 + (size_t)64 * ldw, lB1);
        __syncthreads();

        f16x8 af[4], bf[4];
#pragma unroll
        for (int i = 0; i < 4; ++i)
            af[i] = *(const f16x8*)&As[(wm * 64 + i * 16 + lr) * 32 + lk * 8];
#pragma unroll
        for (int i = 0; i < 4; ++i)
            bf[i] = *(const f16x8*)&Bs[(wn * 64 + i * 16 + lr) * 32 + lk * 8];
#pragma unroll
        for (int mi = 0; mi < 4; ++mi)
#pragma unroll
            for (int ni = 0; ni < 4; ++ni)
                acc[mi][ni] = __builtin_amdgcn_mfma_f32_16x16x32_f16(
                    af[mi], bf[ni], acc[mi][ni], 0, 0, 0);
    }

#pragma unroll
    for (int mi = 0; mi < 4; ++mi) {
#pragma unroll
        for (int ni = 0; ni < 4; ++ni) {
#pragma unroll
            for (int j = 0; j < 4; ++j) {
                int r = row0 + wm * 64 + mi * 16 + lk * 4 + j;
                int c = col0 + wn * 64 + ni * 16 + lr;
                float v = acc[mi][ni][j];
                if (BIAS) v += bias[c] * bscale;
                if (RELU) v = fmaxf(v, 0.0f);
                C[(size_t)r * ldc + c] = (f16)v;
            }
        }
    }
}

// ---------------------------------------------------------------------------
// Fused GEMM + bias + LayerNorm + relu (node MLP layer 2). BM=64, 8 waves,
// K=512, W row-stride 512. XOR-slot swizzled staging (coalesced).
// ---------------------------------------------------------------------------
__global__ __launch_bounds__(512, 2)
void fused_gemm_ln(const f16* __restrict__ A, int lda,
                   const f16* __restrict__ W,
                   const float* __restrict__ bias,
                   const float* __restrict__ g, const float* __restrict__ b,
                   f16* __restrict__ C, int ldc)
{
    constexpr int BM = 64, NI = 4, NWN = 8;
    __shared__ f16 As[BM * 32];
    __shared__ f16 Bs[512 * 32];
    __shared__ float lnred[BM * NWN * 2];
    __shared__ float stat[BM * 2];

    const int tid  = threadIdx.x;
    const int wave = tid >> 6;
    const int lane = tid & 63;
    const int wn = wave;
    const int lr = lane & 15, lk = lane >> 4;
    const int row0 = blockIdx.x * BM;
    const int wcol0 = wn * (NI * 16);

    const int c16 = (((tid & 3) ^ ((tid >> 3) & 3)) << 3);
    const f16* Ar = A + (size_t)(row0 + (tid >> 2)) * lda + c16;
    const f16* Wr = W + (size_t)(tid >> 2) * 512 + c16;
    const int kx = (lk ^ ((lr >> 1) & 3)) << 3;

    f32x4 acc[4][NI] = {};

    for (int k0 = 0; k0 < 512; k0 += 32) {
        if (k0) __syncthreads();
#pragma unroll
        for (int i = 0; i < 4; ++i)
            gl_lds16(Wr + k0 + (size_t)(i * 128) * 512, &Bs[(i * 512 + tid) * 8]);
        if (tid < 256)
            gl_lds16(Ar + k0, &As[tid * 8]);
        __syncthreads();

        f16x8 af[4], bf[NI];
#pragma unroll
        for (int i = 0; i < 4; ++i)
            af[i] = *(const f16x8*)&As[(i * 16 + lr) * 32 + kx];
#pragma unroll
        for (int i = 0; i < NI; ++i)
            bf[i] = *(const f16x8*)&Bs[(wcol0 + i * 16 + lr) * 32 + kx];
#pragma unroll
        for (int mi = 0; mi < 4; ++mi)
#pragma unroll
            for (int ni = 0; ni < NI; ++ni)
                acc[mi][ni] = __builtin_amdgcn_mfma_f32_16x16x32_f16(
                    af[mi], bf[ni], acc[mi][ni], 0, 0, 0);
    }

    float biasv[NI], gv[NI], bv[NI];
#pragma unroll
    for (int ni = 0; ni < NI; ++ni) {
        int col = wcol0 + ni * 16 + lr;
        biasv[ni] = bias[col];
        gv[ni] = g[col];
        bv[ni] = b[col];
    }
#pragma unroll
    for (int mi = 0; mi < 4; ++mi)
#pragma unroll
        for (int ni = 0; ni < NI; ++ni)
#pragma unroll
            for (int j = 0; j < 4; ++j)
                acc[mi][ni][j] += biasv[ni];

#pragma unroll
    for (int mi = 0; mi < 4; ++mi) {
#pragma unroll
        for (int j = 0; j < 4; ++j) {
            float s = 0.f, s2 = 0.f;
#pragma unroll
            for (int ni = 0; ni < NI; ++ni) {
                float v = acc[mi][ni][j];
                s += v; s2 += v * v;
            }
#pragma unroll
            for (int o = 1; o < 16; o <<= 1) {
                s  += __shfl_xor(s,  o, 64);
                s2 += __shfl_xor(s2, o, 64);
            }
            if (lr == 0) {
                int row = mi * 16 + lk * 4 + j;
                lnred[(row * NWN + wn) * 2 + 0] = s;
                lnred[(row * NWN + wn) * 2 + 1] = s2;
            }
        }
    }
    __syncthreads();
    if (tid < BM) {
        float s = 0.f, s2 = 0.f;
#pragma unroll
        for (int w = 0; w < NWN; ++w) {
            s  += lnred[(tid * NWN + w) * 2 + 0];
            s2 += lnred[(tid * NWN + w) * 2 + 1];
        }
        float mean = s * (1.0f / 512.0f);
        float var  = fmaxf(s2 * (1.0f / 512.0f) - mean * mean, 0.0f);
        stat[tid * 2 + 0] = mean;
        stat[tid * 2 + 1] = rsqrtf(var + 1e-5f);
    }
    __syncthreads();

#pragma unroll
    for (int mi = 0; mi < 4; ++mi) {
#pragma unroll
        for (int j = 0; j < 4; ++j) {
            int row = mi * 16 + lk * 4 + j;
            float mean = stat[row * 2 + 0];
            float rstd = stat[row * 2 + 1];
            size_t gr = (size_t)(row0 + row) * ldc;
#pragma unroll
            for (int ni = 0; ni < NI; ++ni) {
                float y = (acc[mi][ni][j] - mean) * rstd * gv[ni] + bv[ni];
                C[gr + wcol0 + ni * 16 + lr] = (f16)fmaxf(y, 0.0f);
            }
        }
    }
}

// ---------------------------------------------------------------------------
// Convert fp32 -> f16. Slots strided into XCAT cols 0:128 (ldc=640).
// ew1 repacked: w_ew1x[1024][128] = [ew1[:, :128] ; ew1[:, 128:]].
// eb1x[1024] f32 = 0.5*[eb1 ; eb1].
// ---------------------------------------------------------------------------
__global__ void convert_all_kernel(
    const float* __restrict__ s0, f16* __restrict__ xcat,
    const float* __restrict__ s1, f16* __restrict__ d1,
    const float* __restrict__ s2, f16* __restrict__ d2,
    const float* __restrict__ s3, f16* __restrict__ d3,
    const float* __restrict__ s4, f16* __restrict__ d4,
    const float* __restrict__ s5, f16* __restrict__ d5,
    const float* __restrict__ s6, f16* __restrict__ d6,
    const float* __restrict__ eb1, float* __restrict__ eb1x)
{
    int q = blockIdx.x * 256 + threadIdx.x;
    if (q >= 852224) return;
    if (q < 524288) {
        const float4 v = *(const float4*)&s0[(size_t)q * 4];
        f16x4 o; o[0]=(f16)v.x; o[1]=(f16)v.y; o[2]=(f16)v.z; o[3]=(f16)v.w;
        int row = q >> 5, col = (q & 31) << 2;
        *(f16x4*)&xcat[(size_t)row * 640 + col] = o;
        return;
    }
    if (q >= 851968) {
        int i = q - 851968;
        int srcq = (i < 128) ? i : i - 128;
        const float4 v = *(const float4*)&eb1[srcq * 4];
        float4 o; o.x = 0.5f*v.x; o.y = 0.5f*v.y; o.z = 0.5f*v.z; o.w = 0.5f*v.w;
        *(float4*)&eb1x[i * 4] = o;
        return;
    }
    if (q < 557056) {
        int i = q - 524288;
        int f = i << 2;
        int n = f >> 8, c = f & 255;
        const float4 v = *(const float4*)&s1[(size_t)f];
        f16x4 o; o[0]=(f16)v.x; o[1]=(f16)v.y; o[2]=(f16)v.z; o[3]=(f16)v.w;
        int dst = (c < 128) ? n * 128 + c : (512 + n) * 128 + (c - 128);
        *(f16x4*)&d1[dst] = o;
        return;
    }
    const float* s; f16* d; int i;
    if      (q < 622592) { s = s2; d = d2; i = q - 557056; }
    else if (q < 688128) { s = s3; d = d3; i = q - 622592; }
    else if (q < 770048) { s = s4; d = d4; i = q - 688128; }
    else if (q < 835584) { s = s5; d = d5; i = q - 770048; }
    else                 { s = s6; d = d6; i = q - 835584; }
    const float4 v = *(const float4*)&s[(size_t)i * 4];
    f16x4 o; o[0]=(f16)v.x; o[1]=(f16)v.y; o[2]=(f16)v.z; o[3]=(f16)v.w;
    *(f16x4*)&d[(size_t)i * 4] = o;
}

// ---------------------------------------------------------------------------
// ln_agg: AGG[node,:] = sum_{t<7} relu(LN(E2[node*7+t,:])*g+b). 1 wave/node.
// ---------------------------------------------------------------------------
__global__ void ln_agg_kernel(const f16* __restrict__ E2,
                              const float* __restrict__ g, const float* __restrict__ b,
                              f16* __restrict__ AGG, int nodes)
{
    int gw   = (blockIdx.x * 256 + threadIdx.x) >> 6;
    int lane = threadIdx.x & 63;
    if (gw >= nodes) return;
    int bb = gw >> 3, n = gw & 7;
    const f16* base = E2 + (((size_t)(bb * 56 + n * 7)) << 9) + (lane << 3);
    f16x8 v[7];
#pragma unroll
    for (int t = 0; t < 7; ++t) v[t] = *(const f16x8*)(base + ((size_t)t << 9));
    float gv[8], bv[8], acc[8] = {};
#pragma unroll
    for (int j = 0; j < 8; ++j) {
        gv[j] = g[(lane << 3) + j];
        bv[j] = b[(lane << 3) + j];
    }
#pragma unroll
    for (int t = 0; t < 7; ++t) {
        float f[8]; float s = 0.f, s2 = 0.f;
#pragma unroll
        for (int j = 0; j < 8; ++j) { f[j] = (float)v[t][j]; s += f[j]; s2 += f[j] * f[j]; }
#pragma unroll
        for (int o = 32; o; o >>= 1) { s += __shfl_xor(s, o, 64); s2 += __shfl_xor(s2, o, 64); }
        float mean = s * (1.0f / 512.0f);
        float var  = fmaxf(s2 * (1.0f / 512.0f) - mean * mean, 0.0f);
        float rstd = rsqrtf(var + 1e-5f);
#pragma unroll
        for (int j = 0; j < 8; ++j)
            acc[j] += fmaxf((f[j] - mean) * rstd * gv[j] + bv[j], 0.0f);
    }
    f16x8 o;
#pragma unroll
    for (int j = 0; j < 8; ++j) o[j] = (f16)acc[j];
    *(f16x8*)&AGG[((size_t)gw << 9) + (lane << 3)] = o;
}

// ---------------------------------------------------------------------------
// out[b,:] = (sum_n x3[b,n,:]) @ head_w^T + head_b
// ---------------------------------------------------------------------------
__global__ void head_kernel(const f16* __restrict__ x3, const float* __restrict__ hw,
                            const float* __restrict__ hb, float* __restrict__ out)
{
    __shared__ float pooled[128];
    int b = blockIdx.x, t = threadIdx.x;   // 128 threads
    float s = 0.f;
#pragma unroll
    for (int n = 0; n < 8; ++n) s += (float)x3[(((size_t)b * 8 + n) << 7) + t];
    pooled[t] = s;
    __syncthreads();
    if (t < 12) {
        float acc = hb[t];
        for (int d = 0; d < 128; ++d) acc += pooled[d] * hw[t * 128 + d];
        out[b * 12 + t] = acc;
    }
}

// ---------------------------------------------------------------------------
extern "C" void kernel_launch(void* const* d_in, const int* in_sizes, int n_in,
                              void* d_out, int out_size, void* d_ws, size_t ws_size,
                              hipStream_t stream)
{
    const float* slots  = (const float*)d_in[0];
    const float* ew1    = (const float*)d_in[1];
    const float* eb1    = (const float*)d_in[2];
    const float* ew2    = (const float*)d_in[3];
    const float* eb2    = (const float*)d_in[4];
    const float* eln_g  = (const float*)d_in[5];
    const float* eln_b  = (const float*)d_in[6];
    const float* ew3    = (const float*)d_in[7];
    const float* eb3    = (const float*)d_in[8];
    const float* nw1    = (const float*)d_in[9];
    const float* nb1    = (const float*)d_in[10];
    const float* nw2    = (const float*)d_in[11];
    const float* nb2    = (const float*)d_in[12];
    const float* nln_g  = (const float*)d_in[13];
    const float* nln_b  = (const float*)d_in[14];
    const float* nw3    = (const float*)d_in[15];
    const float* nb3    = (const float*)d_in[16];
    const float* head_w = (const float*)d_in[17];
    const float* head_b = (const float*)d_in[18];

    char* ws = (char*)d_ws;
    f16*   XCAT    = (f16*)(ws + 0);            // 20,971,520
    f16*   w_ew1x  = (f16*)(ws + 20971520);     //   262,144  [1024][128]
    f16*   w_ew2   = (f16*)(ws + 21233664);     //   524,288
    f16*   w_ew3   = (f16*)(ws + 21757952);     //   524,288
    f16*   w_nw1   = (f16*)(ws + 22282240);     //   655,360
    f16*   w_nw2   = (f16*)(ws + 22937600);     //   524,288
    f16*   w_nw3   = (f16*)(ws + 23461888);     //   131,072
    float* eb1x    = (float*)(ws + 23592960);   //     4,096  [1024] f32
    f16*   AGG     = (f16*)(ws + 23597056);     // 16,777,216
    char*  arena   =        ws + 40374272;      // 73728*BCH bytes

    // arena = PQc(16384*BCH) + E2c(57344*BCH)
    const size_t FIXED = 40374272ULL;
    int BCH;
    if      (ws_size >= FIXED + 73728ULL * 2048) BCH = 2048;  // 191.4 MB
    else if (ws_size >= FIXED + 73728ULL * 1024) BCH = 1024;  // 115.9 MB
    else                                         BCH = 512;   //  78.1 MB
    const int nch = 2048 / BCH;
    const int RN  = BCH * 8;    // node rows / chunk
    const int RE  = BCH * 56;   // edge rows / chunk (mult 128)

    f16* PQc = (f16*)(arena);                                  // 16384*BCH B
    f16* E2c = (f16*)(arena + (size_t)16384 * BCH);            // 57344*BCH B

    f16* X1 = AGG;
    f16* X2 = (f16*)(arena);
    f16* X3 = (f16*)(arena + 16777216);
    float* out = (float*)d_out;

    convert_all_kernel<<<dim3(3329), 256, 0, stream>>>(
        slots, XCAT, ew1, w_ew1x, ew2, w_ew2, ew3, w_ew3,
        nw1, w_nw1, nw2, w_nw2, nw3, w_nw3, eb1, eb1x);

    for (int c = 0; c < nch; ++c) {
        const f16* sc = XCAT + (size_t)c * RN * 640;
        // PQ = slots @ [ew1_P; ew1_Q]^T + 0.5*[eb1;eb1]   (one N=1024 GEMM)
        gemm_swz_kernel<false><<<dim3(4, RN/128), 256, 0, stream>>>(
            sc, 640, w_ew1x, 128, eb1x, 1.0f, PQc, 1024, 128);
        // e2 = relu(P[src]+Q[tgt]) @ ew2^T + eb2   (fused; no E1; BK=64)
        edge_gemm_fused<<<dim3(2, RE/128), 256, 0, stream>>>(
            PQc, w_ew2, eb2, E2c);
        // agg = segsum(relu(LN(e2)))
        ln_agg_kernel<<<dim3(RN/4), 256, 0, stream>>>(
            E2c, eln_g, eln_b, AGG + (size_t)c * RN * 512, RN);
    }

    // xcat[:,128:640] = AGG @ ew3^T + 7*eb3   (linearity of segment-sum)
    gemm_swz_kernel<false><<<dim3(2,128), 256, 0, stream>>>(
        AGG, 512, w_ew3, 512, eb3, 7.0f, XCAT + 128, 640, 512);
    // x1 = relu(xcat @ nw1^T + nb1)
    gemm_swz_kernel<true><<<dim3(2,128), 256, 0, stream>>>(
        XCAT, 640, w_nw1, 640, nb1, 1.0f, X1, 512, 640);
    // x2 = relu(LN(x1 @ nw2^T + nb2))
    fused_gemm_ln<<<dim3(256), 512, 0, stream>>>(
        X1, 512, w_nw2, nb2, nln_g, nln_b, X2, 512);
    // x3 = relu(x2 @ nw3^T + nb3)
    gemm_kernel<true,true><<<dim3(1,128), 256, 0, stream>>>(
        X2, 512, w_nw3, 512, nb3, 1.0f, X3, 128, 512);

    head_kernel<<<dim3(2048), 128, 0, stream>>>(X3, head_w, head_b, out);
}